// Round 1
// baseline (28139.871 us; speedup 1.0000x reference)
//
#include <hip/hip_runtime.h>

// Model dims
#define BB 2
#define TT 2048
#define EE 1024
#define HH 16
#define HDD 64
#define VV 32000
#define LL 4
#define FF 4096
#define BT (BB*TT)   // 4096

#define NEG_INF (-__builtin_inff())

// ---------------- block reduction helpers (256 threads = 4 waves) ----------------
__device__ inline float blockReduceSum256(float v) {
  #pragma unroll
  for (int off = 32; off > 0; off >>= 1) v += __shfl_xor(v, off, 64);
  __shared__ float t[4];
  __syncthreads();
  if ((threadIdx.x & 63) == 0) t[threadIdx.x >> 6] = v;
  __syncthreads();
  return t[0] + t[1] + t[2] + t[3];
}

__device__ inline float blockReduceMax256(float v) {
  #pragma unroll
  for (int off = 32; off > 0; off >>= 1) v = fmaxf(v, __shfl_xor(v, off, 64));
  __shared__ float t[4];
  __syncthreads();
  if ((threadIdx.x & 63) == 0) t[threadIdx.x >> 6] = v;
  __syncthreads();
  return fmaxf(fmaxf(t[0], t[1]), fmaxf(t[2], t[3]));
}

// ---------------- embedding ----------------
__global__ __launch_bounds__(256) void embed_kernel(
    const int* __restrict__ idx, const float* __restrict__ tok,
    const float* __restrict__ pos, float* __restrict__ x) {
  long i = (long)blockIdx.x * 256 + threadIdx.x;  // over BT*EE
  int e = (int)(i % EE);
  long bt = i / EE;
  int t = (int)(bt % TT);
  x[i] = tok[(long)idx[bt] * EE + e] + pos[(long)t * EE + e];
}

// ---------------- layernorm: one block per row of E=1024 ----------------
__global__ __launch_bounds__(256) void layernorm_kernel(
    const float* __restrict__ x, const float* __restrict__ g,
    const float* __restrict__ b, float* __restrict__ out) {
  int row = blockIdx.x;
  const float* xr = x + (long)row * EE;
  float* orow = out + (long)row * EE;
  int tid = threadIdx.x;
  float local[4];
  float s = 0.f;
  #pragma unroll
  for (int i = 0; i < 4; ++i) { local[i] = xr[tid + i * 256]; s += local[i]; }
  s = blockReduceSum256(s);
  float mean = s * (1.0f / EE);
  float vs = 0.f;
  #pragma unroll
  for (int i = 0; i < 4; ++i) { float d = local[i] - mean; vs += d * d; }
  vs = blockReduceSum256(vs);
  float rstd = rsqrtf(vs * (1.0f / EE) + 1e-5f);
  #pragma unroll
  for (int i = 0; i < 4; ++i) {
    int c = tid + i * 256;
    orow[c] = (local[i] - mean) * rstd * g[c] + b[c];
  }
}

// ---------------- generic tiled f32 GEMM ----------------
// C[m,n] = sum_k A[m,k]*B[k,n] (+bias[n]) (+res[m,n]) (relu?)
// batched over blockIdx.z: A += (z/zdiv)*sA, B += (z%zdiv)*sB, C/res += z*sC
// Tiles: 64x64 out, BK=16, 256 threads, 4x4 per thread. Dims must divide.
__global__ __launch_bounds__(256) void gemm_f32(
    const float* __restrict__ A, const float* __restrict__ B,
    const float* __restrict__ bias, const float* __restrict__ res,
    float* __restrict__ C, int M, int N, int K, int relu,
    int zdiv, long sA, long sB, long sC) {
  int z = blockIdx.z;
  A += (long)(z / zdiv) * sA;
  B += (long)(z % zdiv) * sB;
  C += (long)z * sC;
  if (res) res += (long)z * sC;

  __shared__ float As[16][65];
  __shared__ float Bs[16][64];
  int tid = threadIdx.x;
  int tx = tid & 15, ty = tid >> 4;     // tx: n-quad, ty: m-quad
  int m0 = blockIdx.y * 64, n0 = blockIdx.x * 64;
  int nn = tid & 63, kk = tid >> 6;

  float acc[4][4] = {};
  for (int k0 = 0; k0 < K; k0 += 16) {
    #pragma unroll
    for (int i = 0; i < 4; ++i)
      As[tx][i * 16 + ty] = A[(long)(m0 + i * 16 + ty) * K + k0 + tx];
    #pragma unroll
    for (int j = 0; j < 4; ++j)
      Bs[j * 4 + kk][nn] = B[(long)(k0 + j * 4 + kk) * N + n0 + nn];
    __syncthreads();
    #pragma unroll
    for (int k = 0; k < 16; ++k) {
      float ra[4], rb[4];
      #pragma unroll
      for (int i = 0; i < 4; ++i) ra[i] = As[k][ty * 4 + i];
      #pragma unroll
      for (int j = 0; j < 4; ++j) rb[j] = Bs[k][tx * 4 + j];
      #pragma unroll
      for (int i = 0; i < 4; ++i)
        #pragma unroll
        for (int j = 0; j < 4; ++j) acc[i][j] += ra[i] * rb[j];
    }
    __syncthreads();
  }
  #pragma unroll
  for (int i = 0; i < 4; ++i) {
    int m = m0 + ty * 4 + i;
    #pragma unroll
    for (int j = 0; j < 4; ++j) {
      int n = n0 + tx * 4 + j;
      float v = acc[i][j];
      if (bias) v += bias[n];
      if (res) v += res[(long)m * N + n];
      if (relu) v = fmaxf(v, 0.f);
      C[(long)m * N + n] = v;
    }
  }
}

// ---------------- causal flash attention, f32, 1 wave per query row ----------------
// q,k,v: [B,H,T,HD] ; out a: [B,T,H*HD]
__global__ __launch_bounds__(64) void attention_kernel(
    const float* __restrict__ q, const float* __restrict__ k,
    const float* __restrict__ v, float* __restrict__ a) {
  int t = blockIdx.x;      // query position
  int bh = blockIdx.y;     // b*H + h
  int b = bh >> 4, hh = bh & 15;
  int lane = threadIdx.x;

  const float* qb = q + ((long)bh * TT + t) * HDD;
  const float* kb = k + (long)bh * TT * HDD;
  const float* vb = v + (long)bh * TT * HDD;

  __shared__ float qs[64];
  __shared__ float ks[64][65];
  __shared__ float vs[64][65];
  __shared__ float wls[64];

  qs[lane] = qb[lane];
  __syncthreads();

  float m = NEG_INF, lsum = 0.f, acc = 0.f;
  for (int s0 = 0; s0 <= t; s0 += 64) {
    #pragma unroll 4
    for (int r = 0; r < 64; ++r) {
      ks[r][lane] = kb[(long)(s0 + r) * HDD + lane];
      vs[r][lane] = vb[(long)(s0 + r) * HDD + lane];
    }
    __syncthreads();
    // score for key s0+lane
    float sc = 0.f;
    const float* krow = ks[lane];
    #pragma unroll
    for (int e = 0; e < 64; ++e) sc += qs[e] * krow[e];
    sc *= 0.125f;  // HD^-0.5
    if (s0 + lane > t) sc = NEG_INF;
    // chunk max (all lanes end with full result)
    float cm = sc;
    #pragma unroll
    for (int off = 32; off > 0; off >>= 1) cm = fmaxf(cm, __shfl_xor(cm, off, 64));
    float m_new = fmaxf(m, cm);
    float alpha = expf(m - m_new);       // exp(-inf) = 0 on first chunk
    float w = expf(sc - m_new);          // masked lanes -> 0
    float csum = w;
    #pragma unroll
    for (int off = 32; off > 0; off >>= 1) csum += __shfl_xor(csum, off, 64);
    lsum = lsum * alpha + csum;
    wls[lane] = w;
    __syncthreads();
    acc *= alpha;
    #pragma unroll 8
    for (int j = 0; j < 64; ++j) acc += wls[j] * vs[j][lane];
    __syncthreads();
    m = m_new;
  }
  // lane holds output dim d = lane
  a[((long)b * TT + t) * EE + hh * HDD + lane] = acc / lsum;
}

// ---------------- loss: per-row log-softmax + target gather ----------------
__global__ __launch_bounds__(256) void loss_row_kernel(
    const float* __restrict__ logits, const int* __restrict__ targets,
    float* __restrict__ row_loss) {
  int r = blockIdx.x;
  const float* lr = logits + (long)r * VV;
  int tid = threadIdx.x;
  float mx = NEG_INF;
  for (int i = tid; i < VV; i += 256) mx = fmaxf(mx, lr[i]);
  mx = blockReduceMax256(mx);
  float se = 0.f;
  for (int i = tid; i < VV; i += 256) se += expf(lr[i] - mx);
  se = blockReduceSum256(se);
  if (tid == 0) row_loss[r] = -(lr[targets[r]] - mx - logf(se));
}

__global__ __launch_bounds__(256) void loss_reduce_kernel(
    const float* __restrict__ row_loss, float* __restrict__ out_loss) {
  int tid = threadIdx.x;
  float s = 0.f;
  for (int i = tid; i < BT; i += 256) s += row_loss[i];
  s = blockReduceSum256(s);
  if (tid == 0) out_loss[0] = s * (1.0f / BT);
}

// ---------------- launch ----------------
extern "C" void kernel_launch(void* const* d_in, const int* in_sizes, int n_in,
                              void* d_out, int out_size, void* d_ws, size_t ws_size,
                              hipStream_t stream) {
  (void)in_sizes; (void)n_in; (void)ws_size;
  const int*   idx     = (const int*)d_in[0];
  const int*   targets = (const int*)d_in[1];
  const float* tok_emb = (const float*)d_in[2];
  const float* pos_emb = (const float*)d_in[3];
  const float* Wq      = (const float*)d_in[4];
  const float* Wk      = (const float*)d_in[5];
  const float* Wv      = (const float*)d_in[6];
  const float* Wproj   = (const float*)d_in[7];
  const float* bproj   = (const float*)d_in[8];
  const float* ln1_g   = (const float*)d_in[9];
  const float* ln1_b   = (const float*)d_in[10];
  const float* ln2_g   = (const float*)d_in[11];
  const float* ln2_b   = (const float*)d_in[12];
  const float* W1      = (const float*)d_in[13];
  const float* b1      = (const float*)d_in[14];
  const float* W2      = (const float*)d_in[15];
  const float* b2      = (const float*)d_in[16];
  const float* lnf_g   = (const float*)d_in[17];
  const float* lnf_b   = (const float*)d_in[18];
  const float* Whead   = (const float*)d_in[19];
  const float* bhead   = (const float*)d_in[20];
  float* out = (float*)d_out;

  // workspace layout (floats)
  float* ws = (float*)d_ws;
  float* x    = ws;                 // [BT,E]      4,194,304
  float* hbuf = ws + 4194304;       // [BT,E]
  float* qb   = ws + 8388608;       // [B,H,T,HD]
  float* kb   = ws + 12582912;
  float* vb   = ws + 16777216;
  float* ab   = ws + 20971520;      // [BT,E]
  float* fb   = ws + 25165824;      // [BT,4E]    16,777,216
  float* row_loss = ws + 41943040;  // [BT]

  embed_kernel<<<BT * EE / 256, 256, 0, stream>>>(idx, tok_emb, pos_emb, x);

  for (int l = 0; l < LL; ++l) {
    layernorm_kernel<<<BT, 256, 0, stream>>>(x, ln1_g + l * EE, ln1_b + l * EE, hbuf);
    // QKV: per (b,h) GEMM  [T,E] @ [E,HD] -> [T,HD]
    dim3 gqkv(1, TT / 64, BB * HH);
    long wl = (long)l * HH * EE * HDD;
    gemm_f32<<<gqkv, 256, 0, stream>>>(hbuf, Wq + wl, nullptr, nullptr, qb,
                                       TT, HDD, EE, 0, HH, (long)TT * EE, (long)EE * HDD, (long)TT * HDD);
    gemm_f32<<<gqkv, 256, 0, stream>>>(hbuf, Wk + wl, nullptr, nullptr, kb,
                                       TT, HDD, EE, 0, HH, (long)TT * EE, (long)EE * HDD, (long)TT * HDD);
    gemm_f32<<<gqkv, 256, 0, stream>>>(hbuf, Wv + wl, nullptr, nullptr, vb,
                                       TT, HDD, EE, 0, HH, (long)TT * EE, (long)EE * HDD, (long)TT * HDD);
    attention_kernel<<<dim3(TT, BB * HH), 64, 0, stream>>>(qb, kb, vb, ab);
    // proj + bias + residual (in-place on x)
    gemm_f32<<<dim3(EE / 64, BT / 64, 1), 256, 0, stream>>>(
        ab, Wproj + (long)l * EE * EE, bproj + l * EE, x, x, BT, EE, EE, 0, 1, 0, 0, 0);
    layernorm_kernel<<<BT, 256, 0, stream>>>(x, ln2_g + l * EE, ln2_b + l * EE, hbuf);
    // MLP
    gemm_f32<<<dim3(FF / 64, BT / 64, 1), 256, 0, stream>>>(
        hbuf, W1 + (long)l * EE * FF, b1 + l * FF, nullptr, fb, BT, FF, EE, 1, 1, 0, 0, 0);
    gemm_f32<<<dim3(EE / 64, BT / 64, 1), 256, 0, stream>>>(
        fb, W2 + (long)l * FF * EE, b2 + l * EE, x, x, BT, EE, FF, 0, 1, 0, 0, 0);
  }

  layernorm_kernel<<<BT, 256, 0, stream>>>(x, lnf_g, lnf_b, hbuf);
  // head: logits -> d_out
  gemm_f32<<<dim3(VV / 64, BT / 64, 1), 256, 0, stream>>>(
      hbuf, Whead, bhead, nullptr, out, BT, VV, EE, 0, 1, 0, 0, 0);

  loss_row_kernel<<<BT, 256, 0, stream>>>(out, targets, row_loss);
  loss_reduce_kernel<<<1, 256, 0, stream>>>(row_loss, out + (long)out_size - 1);
}